// Round 11
// baseline (2013.558 us; speedup 1.0000x reference)
//
#include <hip/hip_runtime.h>
#include <hip/hip_bf16.h>
#include <stdint.h>

#define BDIM 1024
#define SDIM 256
#define VDIM 32000
#define EDIM 300
#define HDIM 256
#define ENCD 768
#define G4H  1024
#define KXI  1344   // 300 + 768 + 256 = 1324 padded to 42*32

typedef short bf16x8 __attribute__((ext_vector_type(8)));
typedef float f32x4  __attribute__((ext_vector_type(4)));

static __device__ __forceinline__ unsigned short f2bf(float f) {
  __hip_bfloat16 b = __float2bfloat16(f);   // RNE
  return *reinterpret_cast<unsigned short*>(&b);
}
static __device__ __forceinline__ unsigned pk2(float x, float y) {
  float2 f; f.x = x; f.y = y;
  __hip_bfloat162 h = __float22bfloat162_rn(f);   // packed RNE (v_cvt_pk_bf16_f32)
  return *reinterpret_cast<unsigned*>(&h);
}
static __device__ __forceinline__ float bf2f(unsigned short u) {
  union { unsigned u; float f; } v; v.u = ((unsigned)u) << 16; return v.f;
}
static __device__ __forceinline__ float sigf(float x) {
  return 1.0f / (1.0f + __expf(-x));
}
static __device__ __forceinline__ float tanh_fast(float x) {
  return 1.0f - 2.0f / (__expf(2.0f * x) + 1.0f);   // saturates correctly at +-inf
}
// swizzled byte offset inside a 32-row encT tile: row stride 1536B, XOR 16B chunks by (row&7)
static __device__ __forceinline__ int swz_off(int row, int kbyte) {
  return row * 1536 + (kbyte ^ ((row & 7) << 4));
}
// raw barrier that does NOT drain vmcnt (keeps global loads in flight);
// lgkmcnt(0) orders LDS ops; sched_barrier pins (rule #18).
static __device__ __forceinline__ void lds_barrier() {
  asm volatile("s_waitcnt lgkmcnt(0)" ::: "memory");
  __builtin_amdgcn_sched_barrier(0);
  __builtin_amdgcn_s_barrier();
  __builtin_amdgcn_sched_barrier(0);
}

// ---------------- prep: bf16 conversions + w_h transpose ----------------
// w_e is packed in MFMA-FRAGMENT ORDER: entry f (16B = 8 bf16):
//   lane = f & 63; n = (f>>6)&1; kt = (f>>7)%24; w = (f>>7)/24
//   j = 32w + 16n + (lane&15); k = 32kt + (lane>>4)*8 + e   (e = 0..7)
__global__ void k_prep(const float* __restrict__ attn_w, const float* __restrict__ w_ih,
                       const float* __restrict__ w_hh, const float* __restrict__ out_w,
                       unsigned short* __restrict__ w_e_frag, float* __restrict__ w_hT,
                       unsigned short* __restrict__ Wb, unsigned short* __restrict__ outw_b) {
  const long NWE = (long)HDIM * ENCD;       // 196608
  const long NWH = (long)HDIM * HDIM;       // 65536
  const long NWB = (long)G4H * KXI;         // 1376256
  const long NOW = (long)VDIM * HDIM;       // 8192000
  const long total = NWE + NWH + NWB + NOW;
  for (long idx = blockIdx.x * 256L + threadIdx.x; idx < total; idx += gridDim.x * 256L) {
    long i = idx;
    if (i < NWE) {
      int e    = (int)(i & 7);
      int f    = (int)(i >> 3);
      int lane = f & 63;
      int n    = (f >> 6) & 1;
      int r2   = f >> 7;          // w*24 + kt
      int kt   = r2 % 24;
      int w    = r2 / 24;
      int j    = 32 * w + 16 * n + (lane & 15);
      int k    = 32 * kt + (lane >> 4) * 8 + e;
      w_e_frag[i] = f2bf(attn_w[j * (4 * HDIM) + HDIM + k]);
    } else if ((i -= NWE) < NWH) {
      int k = (int)(i / HDIM), j = (int)(i % HDIM);
      w_hT[i] = attn_w[j * (4 * HDIM) + k];
    } else if ((i -= NWH) < NWB) {
      int g = (int)(i / KXI), k = (int)(i % KXI);
      float v = 0.f;
      if (k < EDIM + ENCD) v = w_ih[(long)g * (EDIM + ENCD) + k];
      else if (k < EDIM + ENCD + HDIM) v = w_hh[(long)g * HDIM + (k - (EDIM + ENCD))];
      Wb[i] = f2bf(v);
    } else {
      i -= NWB;
      outw_b[i] = f2bf(out_w[i]);
    }
  }
}

// ---------------- hwb[b][j] = h[b] . w_h[j] + attn_b[j] ----------------
__global__ void k_hwb(const float* __restrict__ h, const float* __restrict__ w_hT,
                      const float* __restrict__ attn_b, float* __restrict__ hwb) {
  int b = blockIdx.x, t = threadIdx.x;
  __shared__ float hl[HDIM];
  hl[t] = h[b * HDIM + t];
  __syncthreads();
  float acc = attn_b[t];
#pragma unroll 8
  for (int k = 0; k < HDIM; ++k) acc += hl[k] * w_hT[k * HDIM + t];
  hwb[b * HDIM + t] = acc;
}

// ---------------- persistent producer/consumer fused energy+scores+softmax+context ----------------
// 576 threads = 8 consumer waves (w 0..7) + 1 producer wave (w 8).
// Producer: stages enc tile t+1 (fp32->bf16, swizzled) into nbuf via a 2-round-deep
//   register pipeline; its vmcnt FIFO holds ONLY staging loads -> true overlap.
// Consumers: B rolling 4-deep from frag table (own FIFO), A from LDS, epilogue
//   operands from LDS (hwb/vw pre-staged). No spill: consumer ~95 VGPR, producer ~80.
// Both roles execute exactly 3 lds_barrier() per tile (no vmcnt drain anywhere).
__launch_bounds__(576)
__global__ void k_energy_ctx(const float* __restrict__ enc, const unsigned short* __restrict__ w_e_frag,
                             const float* __restrict__ hwb, const float* __restrict__ v_w,
                             float* __restrict__ ctx_part, float* __restrict__ denom_part) {
  const int t = threadIdx.x;
  const int lane = t & 63;
  const int w = t >> 6;          // 0..7 consumers, 8 producer
  const bool producer = (w == 8);
  const int li = lane & 15;
  const int lg = lane >> 4;
  const int jw = 32 * w;         // consumers only

  __shared__ __align__(16) unsigned short encT[2][32 * ENCD];   // 2 x 48KB, swizzled
  __shared__ float scores_lds[8 * 32];
  __shared__ float p_lds[32];
  __shared__ float hwb_lds[4 * 256];   // 4 b-rows per WG
  __shared__ float vw_lds[256];

  const int NT = 32;
  const int tile0 = blockIdx.x * NT;   // 256 WGs x 32 tiles = 8192

  // producer staging helpers (8 float4 per round per lane; 12 rounds = 32x768 floats)
  auto issue8 = [&](float4* bank, int r, const float* src) {
#pragma unroll
    for (int i = 0; i < 8; ++i)
      bank[i] = *(const float4*)(src + (r * 512 + i * 64 + lane) * 4);
  };
  auto write8 = [&](float4* bank, int r, char* dst) {
#pragma unroll
    for (int i = 0; i < 8; ++i) {
      const int slot = r * 512 + i * 64 + lane;
      const int flat = slot * 4;
      const int row = flat / ENCD;
      const int col = flat - row * ENCD;
      uint2 pk;
      pk.x = pk2(bank[i].x, bank[i].y);
      pk.y = pk2(bank[i].z, bank[i].w);
      *(uint2*)(dst + swz_off(row, col * 2)) = pk;
    }
  };

  // ---- prologue ----
  if (producer) {
    // stage tile0 into buf0 (full 12-round pipeline)
    const float* src0 = enc + (long)tile0 * 32 * ENCD;
    char* dst0 = (char*)&encT[0][0];
    float4 sA[8], sB[8];
    issue8(sA, 0, src0); issue8(sB, 1, src0);
    write8(sA, 0, dst0); issue8(sA, 2, src0);
    write8(sB, 1, dst0); issue8(sB, 3, src0);
    write8(sA, 2, dst0); issue8(sA, 4, src0);
    write8(sB, 3, dst0); issue8(sB, 5, src0);
    write8(sA, 4, dst0); issue8(sA, 6, src0);
    write8(sB, 5, dst0); issue8(sB, 7, src0);
    write8(sA, 6, dst0); issue8(sA, 8, src0);
    write8(sB, 7, dst0); issue8(sB, 9, src0);
    write8(sA, 8, dst0); issue8(sA, 10, src0);
    write8(sB, 9, dst0); issue8(sB, 11, src0);
    write8(sA, 10, dst0);
    write8(sB, 11, dst0);
  } else {
    const int b0 = tile0 >> 3;           // 4 consecutive b rows per WG
    for (int i = t; i < 1024; i += 512) hwb_lds[i] = hwb[b0 * 256 + i];
    if (t < 256) vw_lds[t] = v_w[t];
  }
  lds_barrier();

  const unsigned short* fragW = w_e_frag + (((long)(w & 7) * 48) * 64 + lane) * 8;
  float vw0 = 0.f, vw1 = 0.f;
  if (!producer) { vw0 = vw_lds[jw + li]; vw1 = vw_lds[jw + 16 + li]; }

  // ---- persistent tile loop (3 barriers per tile in BOTH roles) ----
  for (int it = 0; it < NT; ++it) {
    const int tile = tile0 + it;
    const int b = tile >> 3, st = tile & 7;
    const char* cbuf = (const char*)&encT[it & 1][0];
    char* nbuf = (char*)&encT[(it + 1) & 1][0];
    const bool more = (it + 1 < NT);

    if (!producer) {
      const float hw0 = hwb_lds[(it >> 3) * 256 + jw + li];
      const float hw1 = hwb_lds[(it >> 3) * 256 + jw + 16 + li];

      // B 4-deep prefetch (1KB coalesced wave-loads, L2-hit; own FIFO)
      bf16x8 bfr[4][2];
#pragma unroll
      for (int p = 0; p < 4; ++p)
#pragma unroll
        for (int n = 0; n < 2; ++n)
          bfr[p][n] = *(const bf16x8*)(fragW + ((p * 2 + n) * 64) * 8);

      f32x4 acc[2][2];
#pragma unroll
      for (int m = 0; m < 2; m++)
#pragma unroll
        for (int n = 0; n < 2; n++) { f32x4 z = {0.f, 0.f, 0.f, 0.f}; acc[m][n] = z; }

      bf16x8 afr[2][2];
#pragma unroll
      for (int p = 0; p < 2; ++p)
#pragma unroll
        for (int m = 0; m < 2; ++m)
          afr[p][m] = *(const bf16x8*)(cbuf + swz_off(16 * m + li, (p * 32 + lg * 8) * 2));
#pragma unroll
      for (int kt = 0; kt < 24; ++kt) {
        const int kb = kt & 3, ka = kt & 1;
#pragma unroll
        for (int m = 0; m < 2; m++)
#pragma unroll
          for (int n = 0; n < 2; n++)
            acc[m][n] = __builtin_amdgcn_mfma_f32_16x16x32_bf16(afr[ka][m], bfr[kb][n], acc[m][n], 0, 0, 0);
        if (kt + 4 < 24) {
#pragma unroll
          for (int n = 0; n < 2; ++n)
            bfr[kb][n] = *(const bf16x8*)(fragW + (((kt + 4) * 2 + n) * 64) * 8);
        }
        if (kt + 2 < 24) {
          const int kn2 = (kt + 2) * 32;
#pragma unroll
          for (int m = 0; m < 2; ++m)
            afr[ka][m] = *(const bf16x8*)(cbuf + swz_off(16 * m + li, (kn2 + lg * 8) * 2));
        }
      }

      // scores: tanh -> *v_w -> j-reduce
      float val[2][4];
#pragma unroll
      for (int m = 0; m < 2; m++)
#pragma unroll
        for (int r = 0; r < 4; r++) {
          float v0 = tanh_fast(acc[m][0][r] + hw0) * vw0 + tanh_fast(acc[m][1][r] + hw1) * vw1;
          v0 += __shfl_xor(v0, 1);
          v0 += __shfl_xor(v0, 2);
          v0 += __shfl_xor(v0, 4);
          v0 += __shfl_xor(v0, 8);
          val[m][r] = v0;
        }
      if (li < 4) {
        scores_lds[w * 32 + 4 * lg + li]      = val[0][li];
        scores_lds[w * 32 + 16 + 4 * lg + li] = val[1][li];
      }
      lds_barrier();   // BAR1

      if (t < 32) {
        float sc = 0.f;
#pragma unroll
        for (int ww = 0; ww < 8; ++ww) sc += scores_lds[ww * 32 + t];
        float p = __expf(sc);   // scores bounded by sum|v_w| ~ 4 -> safe unnormalized
        p_lds[t] = p;
        float dsum = p;
        dsum += __shfl_xor(dsum, 1);
        dsum += __shfl_xor(dsum, 2);
        dsum += __shfl_xor(dsum, 4);
        dsum += __shfl_xor(dsum, 8);
        dsum += __shfl_xor(dsum, 16);
        if (t == 0) denom_part[b * 8 + st] = dsum;
      }
      lds_barrier();   // BAR2

      // context from the LDS-resident bf16 tile
      if (t < 384) {
        float cx = 0.f, cy = 0.f;
#pragma unroll
        for (int s = 0; s < 32; ++s) {
          float p = p_lds[s];
          unsigned u = *(const unsigned*)(cbuf + swz_off(s, 4 * t));
          cx += p * bf2f((unsigned short)(u & 0xffffu));
          cy += p * bf2f((unsigned short)(u >> 16));
        }
        float* cp = ctx_part + (long)(b * 8 + st) * ENCD + 2 * t;
        cp[0] = cx; cp[1] = cy;
      }
      lds_barrier();   // BAR3 (context ds_reads of cbuf drained by lgkmcnt(0))
    } else {
      // -------- producer: stage tile+1 into nbuf, 12 rounds split 6/4/2 --------
      const float* src = enc + (long)(tile + 1) * 32 * ENCD;
      float4 sA[8], sB[8];
      if (more) {
        issue8(sA, 0, src); issue8(sB, 1, src);
        write8(sA, 0, nbuf); issue8(sA, 2, src);
        write8(sB, 1, nbuf); issue8(sB, 3, src);
        write8(sA, 2, nbuf); issue8(sA, 4, src);
        write8(sB, 3, nbuf); issue8(sB, 5, src);
      }
      lds_barrier();   // BAR1
      if (more) {
        write8(sA, 4, nbuf); issue8(sA, 6, src);
        write8(sB, 5, nbuf); issue8(sB, 7, src);
        write8(sA, 6, nbuf); issue8(sA, 8, src);
        write8(sB, 7, nbuf); issue8(sB, 9, src);
      }
      lds_barrier();   // BAR2
      if (more) {
        write8(sA, 8, nbuf);  issue8(sA, 10, src);
        write8(sB, 9, nbuf);  issue8(sB, 11, src);
        write8(sA, 10, nbuf);
        write8(sB, 11, nbuf);
      }
      lds_barrier();   // BAR3 (lgkmcnt(0) makes nbuf writes visible)
    }
  }
}

// ---------------- build xi = [emb[x] | ctx | h | pad] as bf16 ----------------
__global__ void k_xi(const int* __restrict__ x, const float* __restrict__ emb,
                     const float* __restrict__ h, const float* __restrict__ ctx_part,
                     const float* __restrict__ denom_part, unsigned short* __restrict__ xi_b) {
  int b = blockIdx.x, t = threadIdx.x;
  float denom = 0.f;
#pragma unroll
  for (int st = 0; st < 8; ++st) denom += denom_part[b * 8 + st];
  float inv = 1.0f / denom;
#pragma unroll
  for (int u = 0; u < 3; ++u) {
    int d = t + 256 * u;
    float s = 0.f;
#pragma unroll
    for (int st = 0; st < 8; ++st) s += ctx_part[(long)(b * 8 + st) * ENCD + d];
    xi_b[(long)b * KXI + EDIM + d] = f2bf(s * inv);
  }
  int xv = x[b];
  for (int cc = t; cc < EDIM; cc += 256)
    xi_b[(long)b * KXI + cc] = f2bf(emb[(long)xv * EDIM + cc]);
  xi_b[(long)b * KXI + EDIM + ENCD + t] = f2bf(h[b * HDIM + t]);
  if (t < KXI - (EDIM + ENCD + HDIM))
    xi_b[(long)b * KXI + (EDIM + ENCD + HDIM) + t] = 0;
}

// ---------------- generic 128x128 bf16 GEMM, C = A * Bt^T + bias ----------------
__launch_bounds__(256)
__global__ void k_gemm_bt(const unsigned short* __restrict__ A, const unsigned short* __restrict__ Bt,
                          const float* __restrict__ bias1, const float* __restrict__ bias2,
                          float* __restrict__ out, int N, int K, int MTILES) {
  int bx = blockIdx.x;
  int mt = bx % MTILES, nt = bx / MTILES;
  int row0 = mt * 128, col0 = nt * 128;
  int t = threadIdx.x, lane = t & 63, w = t >> 6;
  int li = lane & 15, lg = lane >> 4;
  int wr = (w >> 1) * 64, wc = (w & 1) * 64;
  __shared__ __align__(16) unsigned short As[2][128 * 32];
  __shared__ __align__(16) unsigned short Bs[2][128 * 32];
  f32x4 acc[4][4];
#pragma unroll
  for (int m = 0; m < 4; m++)
#pragma unroll
    for (int n = 0; n < 4; n++) { f32x4 z = {0.f, 0.f, 0.f, 0.f}; acc[m][n] = z; }

  auto stage = [&](int buf, int k0) {
#pragma unroll
    for (int rep = 0; rep < 2; ++rep) {
      int slot = t + rep * 256;
      int r = slot >> 2, sg = slot & 3;
      uint4 va = *(const uint4*)(A + (long)(row0 + r) * K + k0 + sg * 8);
      uint4 vb = *(const uint4*)(Bt + (long)(col0 + r) * K + k0 + sg * 8);
      *(uint4*)&As[buf][r * 32 + sg * 8] = va;
      *(uint4*)&Bs[buf][r * 32 + sg * 8] = vb;
    }
  };

  stage(0, 0);
  __syncthreads();
  const int nk = K / 32;
  for (int kt = 0; kt < nk; ++kt) {
    if (kt + 1 < nk) stage((kt + 1) & 1, (kt + 1) * 32);
    int cb = kt & 1;
    bf16x8 a[4], bb[4];
#pragma unroll
    for (int m = 0; m < 4; m++) a[m] = *(const bf16x8*)&As[cb][(wr + 16 * m + li) * 32 + lg * 8];
#pragma unroll
    for (int n = 0; n < 4; n++) bb[n] = *(const bf16x8*)&Bs[cb][(wc + 16 * n + li) * 32 + lg * 8];
#pragma unroll
    for (int m = 0; m < 4; m++)
#pragma unroll
      for (int n = 0; n < 4; n++)
        acc[m][n] = __builtin_amdgcn_mfma_f32_16x16x32_bf16(a[m], bb[n], acc[m][n], 0, 0, 0);
    __syncthreads();
  }

#pragma unroll
  for (int n = 0; n < 4; n++) {
    int col = col0 + wc + 16 * n + li;
    float bs = bias1[col];
    if (bias2) bs += bias2[col];
#pragma unroll
    for (int m = 0; m < 4; m++) {
      int rb = row0 + wr + 16 * m + lg * 4;
#pragma unroll
      for (int r = 0; r < 4; r++)
        out[(long)(rb + r) * N + col] = acc[m][n][r] + bs;
    }
  }
}

// ---------------- LSTM pointwise ----------------
__global__ void k_lstm(const float* __restrict__ gates, const float* __restrict__ c,
                       float* __restrict__ h2, float* __restrict__ c2,
                       unsigned short* __restrict__ h2b) {
  int b = blockIdx.x, j = threadIdx.x;
  const float* g = gates + (long)b * G4H;
  float ig = sigf(g[j]);
  float fg = sigf(g[HDIM + j]);
  float gg = tanh_fast(g[2 * HDIM + j]);
  float og = sigf(g[3 * HDIM + j]);
  float cv = c[b * HDIM + j];
  float c2v = fg * cv + ig * gg;
  float h2v = og * tanh_fast(c2v);
  c2[b * HDIM + j] = c2v;
  h2[b * HDIM + j] = h2v;
  h2b[b * HDIM + j] = f2bf(h2v);
}

extern "C" void kernel_launch(void* const* d_in, const int* in_sizes, int n_in,
                              void* d_out, int out_size, void* d_ws, size_t ws_size,
                              hipStream_t stream) {
  const int*   x      = (const int*)d_in[0];
  const float* h      = (const float*)d_in[1];
  const float* c      = (const float*)d_in[2];
  const float* enc    = (const float*)d_in[3];
  const float* emb    = (const float*)d_in[4];
  const float* attn_w = (const float*)d_in[5];
  const float* attn_b = (const float*)d_in[6];
  const float* v_w    = (const float*)d_in[7];
  const float* w_ih   = (const float*)d_in[8];
  const float* w_hh   = (const float*)d_in[9];
  const float* b_ih   = (const float*)d_in[10];
  const float* b_hh   = (const float*)d_in[11];
  const float* out_w  = (const float*)d_in[12];
  const float* out_b  = (const float*)d_in[13];
  float* out = (float*)d_out;

  // workspace layout (bytes)
  char* ws = (char*)d_ws;
  float* hwb             = (float*)(ws + 0);                 // 1,048,576
  unsigned short* w_e_fr = (unsigned short*)(ws + 1048576);  //   393,216
  float* w_hT            = (float*)(ws + 1441792);           //   262,144
  float* ctx_part        = (float*)(ws + 1703936);           // 25,165,824
  float* denom_part      = (float*)(ws + 26869760);          //    32,768
  unsigned short* Wb     = (unsigned short*)(ws + 26902528); // 2,752,512
  unsigned short* xi_b   = (unsigned short*)(ws + 29655040); // 2,752,512
  float* gates           = (float*)(ws + 32407552);          // 4,194,304
  unsigned short* h2b    = (unsigned short*)(ws + 36601856); //   524,288
  unsigned short* outw_b = (unsigned short*)(ws + 37126144); // 16,384,000 -> end 53,510,144
  if (ws_size < 53510144u) return;

  k_prep<<<2048, 256, 0, stream>>>(attn_w, w_ih, w_hh, out_w, w_e_fr, w_hT, Wb, outw_b);
  k_hwb<<<1024, 256, 0, stream>>>(h, w_hT, attn_b, hwb);
  k_energy_ctx<<<256, 576, 0, stream>>>(enc, w_e_fr, hwb, v_w, ctx_part, denom_part);
  k_xi<<<1024, 256, 0, stream>>>(x, emb, h, ctx_part, denom_part, xi_b);
  k_gemm_bt<<<64, 256, 0, stream>>>(xi_b, Wb, b_ih, b_hh, gates, G4H, KXI, 8);
  k_lstm<<<1024, 256, 0, stream>>>(gates, c, out + (long)BDIM * VDIM,
                                   out + (long)BDIM * VDIM + (long)BDIM * HDIM, h2b);
  k_gemm_bt<<<2000, 256, 0, stream>>>(h2b, outw_b, out_b, nullptr, out, VDIM, HDIM, 8);
}

// Round 12
// 382.096 us; speedup vs baseline: 5.2698x; 5.2698x over previous
//
#include <hip/hip_runtime.h>
#include <hip/hip_bf16.h>
#include <stdint.h>

#define BDIM 1024
#define SDIM 256
#define VDIM 32000
#define EDIM 300
#define HDIM 256
#define ENCD 768
#define G4H  1024
#define KXI  1344   // 300 + 768 + 256 = 1324 padded to 42*32

typedef short bf16x8 __attribute__((ext_vector_type(8)));
typedef float f32x4  __attribute__((ext_vector_type(4)));

static __device__ __forceinline__ unsigned short f2bf(float f) {
  __hip_bfloat16 b = __float2bfloat16(f);   // RNE
  return *reinterpret_cast<unsigned short*>(&b);
}
static __device__ __forceinline__ unsigned pk2(float x, float y) {
  float2 f; f.x = x; f.y = y;
  __hip_bfloat162 h = __float22bfloat162_rn(f);   // packed RNE (v_cvt_pk_bf16_f32)
  return *reinterpret_cast<unsigned*>(&h);
}
static __device__ __forceinline__ float bf2f(unsigned short u) {
  union { unsigned u; float f; } v; v.u = ((unsigned)u) << 16; return v.f;
}
static __device__ __forceinline__ float sigf(float x) {
  return 1.0f / (1.0f + __expf(-x));
}
static __device__ __forceinline__ float tanh_fast(float x) {
  return 1.0f - 2.0f / (__expf(2.0f * x) + 1.0f);   // saturates correctly at +-inf
}
// swizzled byte offset inside encT tile: row stride 1536B, XOR 16B chunks by (row&7)
static __device__ __forceinline__ int swz_off(int row, int kbyte) {
  return row * 1536 + (kbyte ^ ((row & 7) << 4));
}

// ---------------- prep: bf16 conversions ----------------
// w_e packed in MFMA-FRAGMENT ORDER (see R8): a wave's B-frag load is one 1KB block.
// Also emits: w_h_b (bf16 [j][k], K=256), h_b (bf16 [b][k]) for the hwb GEMM.
__global__ void k_prep(const float* __restrict__ attn_w, const float* __restrict__ w_ih,
                       const float* __restrict__ w_hh, const float* __restrict__ out_w,
                       const float* __restrict__ h,
                       unsigned short* __restrict__ w_e_frag, unsigned short* __restrict__ w_h_b,
                       unsigned short* __restrict__ h_b,
                       unsigned short* __restrict__ Wb, unsigned short* __restrict__ outw_b) {
  const long NWE = (long)HDIM * ENCD;       // 196608
  const long NW1 = (long)HDIM * HDIM;       // 65536  (w_h_b)
  const long NHB = (long)BDIM * HDIM;       // 262144 (h_b)
  const long NWB = (long)G4H * KXI;         // 1376256
  const long NOW = (long)VDIM * HDIM;       // 8192000
  const long total = NWE + NW1 + NHB + NWB + NOW;
  for (long idx = blockIdx.x * 256L + threadIdx.x; idx < total; idx += gridDim.x * 256L) {
    long i = idx;
    if (i < NWE) {
      int e    = (int)(i & 7);
      int f    = (int)(i >> 3);
      int lane = f & 63;
      int n    = (f >> 6) & 1;
      int r2   = f >> 7;          // w*24 + kt
      int kt   = r2 % 24;
      int w    = r2 / 24;
      int j    = 32 * w + 16 * n + (lane & 15);
      int k    = 32 * kt + (lane >> 4) * 8 + e;
      w_e_frag[i] = f2bf(attn_w[j * (4 * HDIM) + HDIM + k]);
    } else if ((i -= NWE) < NW1) {
      int j = (int)(i / HDIM), k = (int)(i % HDIM);
      w_h_b[i] = f2bf(attn_w[j * (4 * HDIM) + k]);
    } else if ((i -= NW1) < NHB) {
      h_b[i] = f2bf(h[i]);
    } else if ((i -= NHB) < NWB) {
      int g = (int)(i / KXI), k = (int)(i % KXI);
      float v = 0.f;
      if (k < EDIM + ENCD) v = w_ih[(long)g * (EDIM + ENCD) + k];
      else if (k < EDIM + ENCD + HDIM) v = w_hh[(long)g * HDIM + (k - (EDIM + ENCD))];
      Wb[i] = f2bf(v);
    } else {
      i -= NWB;
      outw_b[i] = f2bf(out_w[i]);
    }
  }
}

// ---------------- fused energy GEMM + tanh + scores + exp + partial context ----------------
// R8 structure (best measured). Single K-loop change: B-frag prefetch depth 4 -> 6
// (12 loads in flight, coverage ~6 kt > ~200cy L2 latency). Peak live regs ~115 < 128.
__launch_bounds__(512, 4)
__global__ void k_energy_ctx(const float* __restrict__ enc, const unsigned short* __restrict__ w_e_frag,
                             const float* __restrict__ hwb, const float* __restrict__ v_w,
                             float* __restrict__ ctx_part, float* __restrict__ denom_part) {
  const int b = blockIdx.x >> 3;
  const int st = blockIdx.x & 7;
  const int s0 = st * 32;
  const int t = threadIdx.x;
  const int lane = t & 63;
  const int w = t >> 6;          // wave 0..7, owns j in [32w, 32w+32)
  const int li = lane & 15;
  const int lg = lane >> 4;

  __shared__ __align__(16) unsigned short encT[32 * ENCD];   // 48KB bf16, swizzled
  __shared__ float scores_lds[8 * 32];
  __shared__ float p_lds[32];

  const float* encB = enc + (long)(b * SDIM + s0) * ENCD;
  const int jw = 32 * w;
  // fragment-ordered B base for this wave: entries ((w*24+kt)*2+n)*64 + lane
  const unsigned short* fragW = w_e_frag + (((long)w * 24 * 2) * 64 + lane) * 8;

  // ---- staging: issue ALL 12 float4 loads first, convert after ----
  float4 sv[12];
#pragma unroll
  for (int u = 0; u < 12; ++u)
    sv[u] = *(const float4*)(encB + 4 * t + 2048 * u);

  // 6-deep B-frag prefetch (kt = 0..5): each load is contiguous 1KB per wave
  bf16x8 bfr[6][2];
#pragma unroll
  for (int p = 0; p < 6; ++p)
#pragma unroll
    for (int n = 0; n < 2; ++n)
      bfr[p][n] = *(const bf16x8*)(fragW + ((p * 2 + n) * 64) * 8);

  // epilogue operands, in flight during the K-loop
  float hw0 = hwb[b * HDIM + jw + li];
  float hw1 = hwb[b * HDIM + jw + 16 + li];
  float vw0 = v_w[jw + li];
  float vw1 = v_w[jw + 16 + li];

  // convert + swizzled LDS write
#pragma unroll
  for (int u = 0; u < 12; ++u) {
    const int flat = 4 * t + 2048 * u;
    const int row = flat / ENCD;
    const int col = flat - row * ENCD;          // multiple of 4
    uint2 pk;
    pk.x = pk2(sv[u].x, sv[u].y);
    pk.y = pk2(sv[u].z, sv[u].w);
    *(uint2*)((char*)encT + swz_off(row, col * 2)) = pk;
  }

  f32x4 acc[2][2];
#pragma unroll
  for (int m = 0; m < 2; m++)
#pragma unroll
    for (int n = 0; n < 2; n++) { f32x4 z = {0.f, 0.f, 0.f, 0.f}; acc[m][n] = z; }

  __syncthreads();   // the ONLY staging barrier

  // 2-deep A-frag (ds_read) prefetch
  bf16x8 afr[2][2];
#pragma unroll
  for (int p = 0; p < 2; ++p)
#pragma unroll
    for (int m = 0; m < 2; ++m)
      afr[p][m] = *(const bf16x8*)((const char*)encT + swz_off(16 * m + li, (p * 32 + lg * 8) * 2));

  // ---- fully-unrolled barrier-free K-loop: 24 steps x 4 MFMA ----
#pragma unroll
  for (int kt = 0; kt < 24; ++kt) {
    const int kb = kt % 6, ka = kt & 1;
#pragma unroll
    for (int m = 0; m < 2; m++)
#pragma unroll
      for (int n = 0; n < 2; n++)
        acc[m][n] = __builtin_amdgcn_mfma_f32_16x16x32_bf16(afr[ka][m], bfr[kb][n], acc[m][n], 0, 0, 0);
    if (kt + 6 < 24) {
#pragma unroll
      for (int n = 0; n < 2; ++n)
        bfr[kb][n] = *(const bf16x8*)(fragW + (((kt + 6) * 2 + n) * 64) * 8);
    }
    if (kt + 2 < 24) {
      const int kn2 = (kt + 2) * 32;
#pragma unroll
      for (int m = 0; m < 2; ++m)
        afr[ka][m] = *(const bf16x8*)((const char*)encT + swz_off(16 * m + li, (kn2 + lg * 8) * 2));
    }
  }

  // epilogue: energy -> tanh -> * v_w -> reduce over j -> scores
  float val[2][4];
#pragma unroll
  for (int m = 0; m < 2; m++)
#pragma unroll
    for (int r = 0; r < 4; r++) {
      float v0 = tanh_fast(acc[m][0][r] + hw0) * vw0 + tanh_fast(acc[m][1][r] + hw1) * vw1;
      v0 += __shfl_xor(v0, 1);
      v0 += __shfl_xor(v0, 2);
      v0 += __shfl_xor(v0, 4);
      v0 += __shfl_xor(v0, 8);
      val[m][r] = v0;
    }
  if (li < 4) {
    scores_lds[w * 32 + 4 * lg + li]      = val[0][li];
    scores_lds[w * 32 + 16 + 4 * lg + li] = val[1][li];
  }
  __syncthreads();
  if (t < 32) {
    float sc = 0.f;
#pragma unroll
    for (int ww = 0; ww < 8; ++ww) sc += scores_lds[ww * 32 + t];
    float p = __expf(sc);   // scores bounded by sum|v_w| ~ 4 -> safe unnormalized
    p_lds[t] = p;
    float dsum = p;
    dsum += __shfl_xor(dsum, 1);
    dsum += __shfl_xor(dsum, 2);
    dsum += __shfl_xor(dsum, 4);
    dsum += __shfl_xor(dsum, 8);
    dsum += __shfl_xor(dsum, 16);
    if (t == 0) denom_part[b * 8 + st] = dsum;
  }
  __syncthreads();
  // partial context from the LDS-resident bf16 tile
  if (t < 384) {
    float cx = 0.f, cy = 0.f;
#pragma unroll
    for (int s = 0; s < 32; ++s) {
      float p = p_lds[s];
      unsigned u = *(const unsigned*)((const char*)encT + swz_off(s, 4 * t));
      cx += p * bf2f((unsigned short)(u & 0xffffu));
      cy += p * bf2f((unsigned short)(u >> 16));
    }
    float* cp = ctx_part + (long)(b * 8 + st) * ENCD + 2 * t;
    cp[0] = cx; cp[1] = cy;
  }
}

// ---------------- build xi = [emb[x] | ctx | h | pad] as bf16 ----------------
__global__ void k_xi(const int* __restrict__ x, const float* __restrict__ emb,
                     const float* __restrict__ h, const float* __restrict__ ctx_part,
                     const float* __restrict__ denom_part, unsigned short* __restrict__ xi_b) {
  int b = blockIdx.x, t = threadIdx.x;
  float denom = 0.f;
#pragma unroll
  for (int st = 0; st < 8; ++st) denom += denom_part[b * 8 + st];
  float inv = 1.0f / denom;
#pragma unroll
  for (int u = 0; u < 3; ++u) {
    int d = t + 256 * u;
    float s = 0.f;
#pragma unroll
    for (int st = 0; st < 8; ++st) s += ctx_part[(long)(b * 8 + st) * ENCD + d];
    xi_b[(long)b * KXI + EDIM + d] = f2bf(s * inv);
  }
  int xv = x[b];
  for (int cc = t; cc < EDIM; cc += 256)
    xi_b[(long)b * KXI + cc] = f2bf(emb[(long)xv * EDIM + cc]);
  xi_b[(long)b * KXI + EDIM + ENCD + t] = f2bf(h[b * HDIM + t]);
  if (t < KXI - (EDIM + ENCD + HDIM))
    xi_b[(long)b * KXI + (EDIM + ENCD + HDIM) + t] = 0;
}

// ---------------- generic 128x128 bf16 GEMM, C = A * Bt^T + bias ----------------
__launch_bounds__(256)
__global__ void k_gemm_bt(const unsigned short* __restrict__ A, const unsigned short* __restrict__ Bt,
                          const float* __restrict__ bias1, const float* __restrict__ bias2,
                          float* __restrict__ out, int N, int K, int MTILES) {
  int bx = blockIdx.x;
  int mt = bx % MTILES, nt = bx / MTILES;
  int row0 = mt * 128, col0 = nt * 128;
  int t = threadIdx.x, lane = t & 63, w = t >> 6;
  int li = lane & 15, lg = lane >> 4;
  int wr = (w >> 1) * 64, wc = (w & 1) * 64;
  __shared__ __align__(16) unsigned short As[2][128 * 32];
  __shared__ __align__(16) unsigned short Bs[2][128 * 32];
  f32x4 acc[4][4];
#pragma unroll
  for (int m = 0; m < 4; m++)
#pragma unroll
    for (int n = 0; n < 4; n++) { f32x4 z = {0.f, 0.f, 0.f, 0.f}; acc[m][n] = z; }

  auto stage = [&](int buf, int k0) {
#pragma unroll
    for (int rep = 0; rep < 2; ++rep) {
      int slot = t + rep * 256;
      int r = slot >> 2, sg = slot & 3;
      uint4 va = *(const uint4*)(A + (long)(row0 + r) * K + k0 + sg * 8);
      uint4 vb = *(const uint4*)(Bt + (long)(col0 + r) * K + k0 + sg * 8);
      *(uint4*)&As[buf][r * 32 + sg * 8] = va;
      *(uint4*)&Bs[buf][r * 32 + sg * 8] = vb;
    }
  };

  stage(0, 0);
  __syncthreads();
  const int nk = K / 32;
  for (int kt = 0; kt < nk; ++kt) {
    if (kt + 1 < nk) stage((kt + 1) & 1, (kt + 1) * 32);
    int cb = kt & 1;
    bf16x8 a[4], bb[4];
#pragma unroll
    for (int m = 0; m < 4; m++) a[m] = *(const bf16x8*)&As[cb][(wr + 16 * m + li) * 32 + lg * 8];
#pragma unroll
    for (int n = 0; n < 4; n++) bb[n] = *(const bf16x8*)&Bs[cb][(wc + 16 * n + li) * 32 + lg * 8];
#pragma unroll
    for (int m = 0; m < 4; m++)
#pragma unroll
      for (int n = 0; n < 4; n++)
        acc[m][n] = __builtin_amdgcn_mfma_f32_16x16x32_bf16(a[m], bb[n], acc[m][n], 0, 0, 0);
    __syncthreads();
  }

#pragma unroll
  for (int n = 0; n < 4; n++) {
    int col = col0 + wc + 16 * n + li;
    float bs = bias1[col];
    if (bias2) bs += bias2[col];
#pragma unroll
    for (int m = 0; m < 4; m++) {
      int rb = row0 + wr + 16 * m + lg * 4;
#pragma unroll
      for (int r = 0; r < 4; r++)
        out[(long)(rb + r) * N + col] = acc[m][n][r] + bs;
    }
  }
}

// ---------------- LSTM pointwise ----------------
__global__ void k_lstm(const float* __restrict__ gates, const float* __restrict__ c,
                       float* __restrict__ h2, float* __restrict__ c2,
                       unsigned short* __restrict__ h2b) {
  int b = blockIdx.x, j = threadIdx.x;
  const float* g = gates + (long)b * G4H;
  float ig = sigf(g[j]);
  float fg = sigf(g[HDIM + j]);
  float gg = tanh_fast(g[2 * HDIM + j]);
  float og = sigf(g[3 * HDIM + j]);
  float cv = c[b * HDIM + j];
  float c2v = fg * cv + ig * gg;
  float h2v = og * tanh_fast(c2v);
  c2[b * HDIM + j] = c2v;
  h2[b * HDIM + j] = h2v;
  h2b[b * HDIM + j] = f2bf(h2v);
}

extern "C" void kernel_launch(void* const* d_in, const int* in_sizes, int n_in,
                              void* d_out, int out_size, void* d_ws, size_t ws_size,
                              hipStream_t stream) {
  const int*   x      = (const int*)d_in[0];
  const float* h      = (const float*)d_in[1];
  const float* c      = (const float*)d_in[2];
  const float* enc    = (const float*)d_in[3];
  const float* emb    = (const float*)d_in[4];
  const float* attn_w = (const float*)d_in[5];
  const float* attn_b = (const float*)d_in[6];
  const float* v_w    = (const float*)d_in[7];
  const float* w_ih   = (const float*)d_in[8];
  const float* w_hh   = (const float*)d_in[9];
  const float* b_ih   = (const float*)d_in[10];
  const float* b_hh   = (const float*)d_in[11];
  const float* out_w  = (const float*)d_in[12];
  const float* out_b  = (const float*)d_in[13];
  float* out = (float*)d_out;

  // workspace layout (bytes)
  char* ws = (char*)d_ws;
  float* hwb             = (float*)(ws + 0);                 // 1,048,576
  unsigned short* w_e_fr = (unsigned short*)(ws + 1048576);  //   393,216
  unsigned short* w_h_b  = (unsigned short*)(ws + 1441792);  //   131,072
  unsigned short* h_b    = (unsigned short*)(ws + 1572864);  //   524,288
  float* ctx_part        = (float*)(ws + 2097152);           // 25,165,824
  float* denom_part      = (float*)(ws + 27262976);          //    32,768
  unsigned short* Wb     = (unsigned short*)(ws + 27295744); // 2,752,512
  unsigned short* xi_b   = (unsigned short*)(ws + 30048256); // 2,752,512
  float* gates           = (float*)(ws + 32800768);          // 4,194,304
  unsigned short* h2b    = (unsigned short*)(ws + 36995072); //   524,288
  unsigned short* outw_b = (unsigned short*)(ws + 37519360); // 16,384,000 -> end 53,903,360
  if (ws_size < 53903360u) return;

  k_prep<<<2048, 256, 0, stream>>>(attn_w, w_ih, w_hh, out_w, h, w_e_fr, w_h_b, h_b, Wb, outw_b);
  k_gemm_bt<<<16, 256, 0, stream>>>(h_b, w_h_b, attn_b, nullptr, hwb, HDIM, HDIM, 8);
  k_energy_ctx<<<8192, 512, 0, stream>>>(enc, w_e_fr, hwb, v_w, ctx_part, denom_part);
  k_xi<<<1024, 256, 0, stream>>>(x, emb, h, ctx_part, denom_part, xi_b);
  k_gemm_bt<<<64, 256, 0, stream>>>(xi_b, Wb, b_ih, b_hh, gates, G4H, KXI, 8);
  k_lstm<<<1024, 256, 0, stream>>>(gates, c, out + (long)BDIM * VDIM,
                                   out + (long)BDIM * VDIM + (long)BDIM * HDIM, h2b);
  k_gemm_bt<<<2000, 256, 0, stream>>>(h2b, outw_b, out_b, nullptr, out, VDIM, HDIM, 8);
}